// Round 1
// baseline (192.048 us; speedup 1.0000x reference)
//
#include <hip/hip_runtime.h>

// LSTM autoencoder via bf16 MFMA, v9: BT=16, 384-thr blocks (6 waves), grid 512
// -> TWO independent barrier domains per CU (LDS 39.4KB/block, 78.8KB total).
// Per-wave ILP kept at v8's 4 chains: 4 tiles x 1 batch-half per wave.
// Per-CU issue counts identical to v8; barrier/dep stalls of one block are
// filled by the other block's compute (v8 was 1 block/CU: VALUBusy 52%,
// everything else idle during the 60 serial barrier regions).
// B=8192, T=30, F=16, H1=64, H2=32.
// Phase A: waves 0..3: z1 tiles {w,w+4,w+8,w+12}; waves 4..5: z2 tiles {4u..4u+3}.
// Phase B: waves 0..3: z4 + rotating proj; waves 4..5: z3.
// log2e folded into weights/biases (gate-g rows x 2log2e); all gates exp2(-acc).
// Fusion: sig(a)*tanh(b) = (1-eb) * rcp((1+ea)*(1+eb)).
// aB (stride 264 u16, 16 rows): phA h1 dbuf p*64, h2 dbuf 128+p*32, latent 160..191;
//                               phB h4 dbuf p*64, latent 160 (preserved), h3 192+p*32.
// LDS: xAll 16x968 (30.25KB) + aB 16x264 (8.25KB) = 39424 B -> 2 blocks/CU.

#define TT 30
#define FF 16
#define NT 384

typedef unsigned short u16t;
typedef __attribute__((ext_vector_type(8))) short short8;
typedef __attribute__((ext_vector_type(4))) short short4v;
typedef __attribute__((ext_vector_type(4))) float floatx4;

#define MFMA(a, b, c) __builtin_amdgcn_mfma_f32_16x16x32_bf16(a, b, c, 0, 0, 0)

#if __has_builtin(__builtin_amdgcn_exp2f)
#define EXP2(x) __builtin_amdgcn_exp2f(x)
#else
#define EXP2(x) exp2f(x)
#endif

template <int P> struct IC { static constexpr int v = P; };

__device__ __forceinline__ float rcpf(float v) { return __builtin_amdgcn_rcpf(v); }
__device__ __forceinline__ u16t f2bf(float f) {
  unsigned int u = __float_as_uint(f);
  u = (u + 0x7FFFu + ((u >> 16) & 1u)) >> 16;
  return (u16t)u;
}
__device__ __forceinline__ short8 ldFragS(const float* p, float s) {
  const float4 lo = *(const float4*)p;
  const float4 hi = *(const float4*)(p + 4);
  short8 r;
  r[0] = (short)f2bf(lo.x * s); r[1] = (short)f2bf(lo.y * s);
  r[2] = (short)f2bf(lo.z * s); r[3] = (short)f2bf(lo.w * s);
  r[4] = (short)f2bf(hi.x * s); r[5] = (short)f2bf(hi.y * s);
  r[6] = (short)f2bf(hi.z * s); r[7] = (short)f2bf(hi.w * s);
  return r;
}
// acc pre-scaled: [i,f,o] x log2e, [g] x 2log2e. lane owns i,f,g,o of one unit.
__device__ __forceinline__ float cellUp(const floatx4 acc, float& c) {
  float ei = EXP2(-acc[0]);
  float ef = EXP2(-acc[1]);
  float eg = EXP2(-acc[2]);
  float eo = EXP2(-acc[3]);
  float fv = rcpf(1.f + ef);
  float P  = (1.f - eg) * rcpf((1.f + ei) * (1.f + eg));   // sig(i)*tanh(g)
  c = fv * c + P;
  float ec = EXP2(-2.885390082f * c);
  return (1.f - ec) * rcpf((1.f + eo) * (1.f + ec));       // sig(o)*tanh(c)
}

__global__ __launch_bounds__(NT, 3) void lstm_ae_mfma9(
    const float* __restrict__ x,
    const float* __restrict__ Wih1, const float* __restrict__ Whh1, const float* __restrict__ b1,
    const float* __restrict__ Wih2, const float* __restrict__ Whh2, const float* __restrict__ b2,
    const float* __restrict__ Wih3, const float* __restrict__ Whh3, const float* __restrict__ b3,
    const float* __restrict__ Wih4, const float* __restrict__ Whh4, const float* __restrict__ b4,
    const float* __restrict__ Wout, const float* __restrict__ bout,
    float* __restrict__ out)
{
  __shared__ __align__(16) u16t xAll[16 * 968];  // x bf16, k16..31 zero-pad, stride 968
  __shared__ __align__(16) u16t aB[16 * 264];    // recurrent state, stride 264

  const int t = threadIdx.x;
  const int w = t >> 6, lane = t & 63;           // 6 waves
  const int q = lane >> 4, n = lane & 15;
  const int q8 = q * 8;
  const int bBase = blockIdx.x * 16;
  const int nlo = n >> 2, ngt = n & 3;
  const int r0 = n * 264;
  const int x0 = n * 968;
  const bool isZ1 = (w < 4);
  const int u = w & 1;                           // for waves 4..5

  const float L1 = 1.442695041f, L2 = 2.885390082f;
  const float sA = (ngt == 2) ? L2 : L1;         // gate-g rows scaled 2log2e

  // ================= init =================
  for (int i = t; i < 16 * 264; i += NT) aB[i] = 0;
  {
    const float* xb = x + (size_t)bBase * (TT * FF);
    for (int i4 = t; i4 < 1920; i4 += NT) {
      int e = i4 * 4;
      int b = e / 480, r = e - b * 480;
      int stp = r >> 4, f = r & 15;
      float4 v = *(const float4*)&xb[e];
      short4v s4 = { (short)f2bf(v.x), (short)f2bf(v.y), (short)f2bf(v.z), (short)f2bf(v.w) };
      *(short4v*)&xAll[b * 968 + stp * 32 + f] = s4;
    }
    for (int i = t; i < 7680; i += NT) {    // zero pads k=16..31
      int b = i / 480, r = i - b * 480;
      int stp = r >> 4, f = r & 15;
      xAll[b * 968 + stp * 32 + 16 + f] = 0;
    }
  }
  const short8 z8 = { 0, 0, 0, 0, 0, 0, 0, 0 };
  short8 wAf[4][3]; floatx4 biasA[4];            // z1 (waves 0..3) or z2 (waves 4..5)
  if (isZ1) {
#pragma unroll
    for (int tt = 0; tt < 4; ++tt) {
      int T = w + 4 * tt;
      int row = ngt * 64 + T * 4 + nlo;
      wAf[tt][0] = z8;
      if (q < 2) wAf[tt][0] = ldFragS(&Wih1[row * 16 + q8], sA);
      wAf[tt][1] = ldFragS(&Whh1[row * 64 + q8], sA);
      wAf[tt][2] = ldFragS(&Whh1[row * 64 + 32 + q8], sA);
#pragma unroll
      for (int r = 0; r < 4; ++r) biasA[tt][r] = b1[r * 64 + T * 4 + q] * (r == 2 ? L2 : L1);
    }
  } else {
#pragma unroll
    for (int tt = 0; tt < 4; ++tt) {
      int T = 4 * u + tt;
      int row = ngt * 32 + T * 4 + nlo;
      wAf[tt][0] = ldFragS(&Wih2[row * 64 + q8], sA);
      wAf[tt][1] = ldFragS(&Wih2[row * 64 + 32 + q8], sA);
      wAf[tt][2] = ldFragS(&Whh2[row * 32 + q8], sA);
#pragma unroll
      for (int r = 0; r < 4; ++r) biasA[tt][r] = b2[r * 32 + T * 4 + q] * (r == 2 ? L2 : L1);
    }
  }
  __syncthreads();

  float cA[4] = {0.f, 0.f, 0.f, 0.f};
  short8 bxN;

  // ---- peel: z1(0) (h1(-1)=0) ----
  if (isZ1) {
    const short8 bx0 = *(const short8*)&xAll[x0 + q8];
#pragma unroll
    for (int tt = 0; tt < 4; ++tt) {
      floatx4 a = biasA[tt];
      a = MFMA(wAf[tt][0], bx0, a);
      aB[r0 + (w + 4 * tt) * 4 + q] = f2bf(cellUp(a, cA[tt]));
    }
    bxN = *(const short8*)&xAll[x0 + 32 + q8];   // prefetch x(1)
  }
  __syncthreads();

  // ================= Phase A: 29 skewed regions, 1 barrier each =================
  auto stepA = [&](int st, auto pc) {
    constexpr int p = decltype(pc)::v;
    const short8 h1a = *(const short8*)&aB[r0 + p * 64 + q8];
    const short8 h1b = *(const short8*)&aB[r0 + p * 64 + 32 + q8];
    if (isZ1) {  // z1(st+1) x4 tiles
#pragma unroll
      for (int tt = 0; tt < 4; ++tt) {
        floatx4 a = biasA[tt];
        a = MFMA(wAf[tt][0], bxN, a);
        a = MFMA(wAf[tt][1], h1a, a);
        a = MFMA(wAf[tt][2], h1b, a);
        aB[r0 + (1 - p) * 64 + (w + 4 * tt) * 4 + q] = f2bf(cellUp(a, cA[tt]));
      }
      const int nx = (st + 2 < TT) ? st + 2 : TT - 1;
      bxN = *(const short8*)&xAll[x0 + nx * 32 + q8];
    } else {     // z2(st) x4 tiles
      const short8 h2 = *(const short8*)&aB[r0 + 128 + (1 - p) * 32 + q8];
#pragma unroll
      for (int tt = 0; tt < 4; ++tt) {
        floatx4 a = biasA[tt];
        a = MFMA(wAf[tt][0], h1a, a);
        a = MFMA(wAf[tt][1], h1b, a);
        a = MFMA(wAf[tt][2], h2, a);
        aB[r0 + 128 + p * 32 + (4 * u + tt) * 4 + q] = f2bf(cellUp(a, cA[tt]));
      }
    }
    __syncthreads();
  };
  for (int st = 0; st < 28; st += 2) { stepA(st, IC<0>{}); stepA(st + 1, IC<1>{}); }
  stepA(28, IC<0>{});
  // ---- tail: z2(29); h1(29)@64, h2(28)@128 -> latent 160..191 ----
  if (!isZ1) {
    const short8 h1a = *(const short8*)&aB[r0 + 64 + q8];
    const short8 h1b = *(const short8*)&aB[r0 + 96 + q8];
    const short8 h2  = *(const short8*)&aB[r0 + 128 + q8];
#pragma unroll
    for (int tt = 0; tt < 4; ++tt) {
      floatx4 a = biasA[tt];
      a = MFMA(wAf[tt][0], h1a, a);
      a = MFMA(wAf[tt][1], h1b, a);
      a = MFMA(wAf[tt][2], h2, a);
      aB[r0 + 160 + (4 * u + tt) * 4 + q] = f2bf(cellUp(a, cA[tt]));
    }
  }
  __syncthreads();

  // ================= transition: phase-B weights; zero h4(-1) =================
  short8 wBf[4][3]; floatx4 biasB[4];
  short8 wof[2]; floatx4 biasO;
  short8 blat;
  if (isZ1) {
#pragma unroll
    for (int tt = 0; tt < 4; ++tt) {
      int T = w + 4 * tt;
      int row = ngt * 64 + T * 4 + nlo;
      wBf[tt][0] = ldFragS(&Wih4[row * 32 + q8], sA);
      wBf[tt][1] = ldFragS(&Whh4[row * 64 + q8], sA);
      wBf[tt][2] = ldFragS(&Whh4[row * 64 + 32 + q8], sA);
#pragma unroll
      for (int r = 0; r < 4; ++r) biasB[tt][r] = b4[r * 64 + T * 4 + q] * (r == 2 ? L2 : L1);
    }
    wof[0] = ldFragS(&Wout[n * 64 + q8], 1.f);
    wof[1] = ldFragS(&Wout[n * 64 + 32 + q8], 1.f);
    biasO = *(const floatx4*)&bout[q * 4];
  } else {
#pragma unroll
    for (int tt = 0; tt < 4; ++tt) {
      int T = 4 * u + tt;
      int row = ngt * 32 + T * 4 + nlo;
      wBf[tt][0] = ldFragS(&Wih3[row * 32 + q8], sA);
      wBf[tt][1] = ldFragS(&Whh3[row * 32 + q8], sA);
#pragma unroll
      for (int r = 0; r < 4; ++r) biasB[tt][r] = b3[r * 32 + T * 4 + q] * (r == 2 ? L2 : L1);
    }
    blat = *(const short8*)&aB[r0 + 160 + q8];
  }
  for (int i = t; i < 1024; i += NT) aB[(i >> 6) * 264 + 64 + (i & 63)] = 0;  // h4(-1)=0
  __syncthreads();

  float cB[4] = {0.f, 0.f, 0.f, 0.f};

  // ---- peel: z3(0) (h3(-1)=0) ----
  if (!isZ1) {
#pragma unroll
    for (int tt = 0; tt < 4; ++tt) {
      floatx4 a = biasB[tt];
      a = MFMA(wBf[tt][0], blat, a);
      aB[r0 + 192 + (4 * u + tt) * 4 + q] = f2bf(cellUp(a, cB[tt]));
    }
  }
  __syncthreads();

  // ================= Phase B: 29 skewed regions, 1 barrier each =================
  auto stepB = [&](int st, auto pc) {
    constexpr int p = decltype(pc)::v;
    const short8 h3 = *(const short8*)&aB[r0 + 192 + p * 32 + q8];
    if (isZ1) {  // z4(st) x4 + rotating proj(st-1)
      const short8 h4a = *(const short8*)&aB[r0 + (1 - p) * 64 + q8];
      const short8 h4b = *(const short8*)&aB[r0 + (1 - p) * 64 + 32 + q8];
#pragma unroll
      for (int tt = 0; tt < 4; ++tt) {
        floatx4 a = biasB[tt];
        a = MFMA(wBf[tt][0], h3, a);
        a = MFMA(wBf[tt][1], h4a, a);
        a = MFMA(wBf[tt][2], h4b, a);
        aB[r0 + p * 64 + (w + 4 * tt) * 4 + q] = f2bf(cellUp(a, cB[tt]));
      }
      if (st > 0 && w == ((st - 1) & 3)) {
        floatx4 y = biasO;
        y = MFMA(wof[0], h4a, y);
        y = MFMA(wof[1], h4b, y);
        *(floatx4*)&out[((size_t)(bBase + n) * TT + (st - 1)) * FF + q * 4] = y;
      }
    } else {     // z3(st+1) x4
#pragma unroll
      for (int tt = 0; tt < 4; ++tt) {
        floatx4 a = biasB[tt];
        a = MFMA(wBf[tt][0], blat, a);
        a = MFMA(wBf[tt][1], h3, a);
        aB[r0 + 192 + (1 - p) * 32 + (4 * u + tt) * 4 + q] = f2bf(cellUp(a, cB[tt]));
      }
    }
    __syncthreads();
  };
  for (int st = 0; st < 28; st += 2) { stepB(st, IC<0>{}); stepB(st + 1, IC<1>{}); }
  stepB(28, IC<0>{});
  // ---- tail: z4(29) (h3(29)@224, h4(28)@0); proj(28); proj(29) ----
  if (isZ1) {
    const short8 h3  = *(const short8*)&aB[r0 + 224 + q8];
    const short8 h4a = *(const short8*)&aB[r0 + q8];
    const short8 h4b = *(const short8*)&aB[r0 + 32 + q8];
#pragma unroll
    for (int tt = 0; tt < 4; ++tt) {
      floatx4 a = biasB[tt];
      a = MFMA(wBf[tt][0], h3, a);
      a = MFMA(wBf[tt][1], h4a, a);
      a = MFMA(wBf[tt][2], h4b, a);
      aB[r0 + 64 + (w + 4 * tt) * 4 + q] = f2bf(cellUp(a, cB[tt]));
    }
    if (w == 0) {  // proj(28)
      floatx4 y = biasO;
      y = MFMA(wof[0], h4a, y);
      y = MFMA(wof[1], h4b, y);
      *(floatx4*)&out[((size_t)(bBase + n) * TT + 28) * FF + q * 4] = y;
    }
  }
  __syncthreads();
  if (w == 1) {  // proj(29): h4(29)@64/96
    const short8 ba = *(const short8*)&aB[r0 + 64 + q8];
    const short8 bb = *(const short8*)&aB[r0 + 96 + q8];
    floatx4 y = biasO;
    y = MFMA(wof[0], ba, y);
    y = MFMA(wof[1], bb, y);
    *(floatx4*)&out[((size_t)(bBase + n) * TT + 29) * FF + q * 4] = y;
  }
}

extern "C" void kernel_launch(void* const* d_in, const int* in_sizes, int n_in,
                              void* d_out, int out_size, void* d_ws, size_t ws_size,
                              hipStream_t stream) {
  const float* x    = (const float*)d_in[0];
  const float* Wih1 = (const float*)d_in[1];
  const float* Whh1 = (const float*)d_in[2];
  const float* b1   = (const float*)d_in[3];
  const float* Wih2 = (const float*)d_in[4];
  const float* Whh2 = (const float*)d_in[5];
  const float* b2   = (const float*)d_in[6];
  const float* Wih3 = (const float*)d_in[7];
  const float* Whh3 = (const float*)d_in[8];
  const float* b3   = (const float*)d_in[9];
  const float* Wih4 = (const float*)d_in[10];
  const float* Whh4 = (const float*)d_in[11];
  const float* b4   = (const float*)d_in[12];
  const float* Wout = (const float*)d_in[13];
  const float* bout = (const float*)d_in[14];
  float* out = (float*)d_out;

  const int B = in_sizes[0] / (TT * FF);   // 8192
  dim3 grid(B / 16), block(NT);
  lstm_ae_mfma9<<<grid, block, 0, stream>>>(
      x, Wih1, Whh1, b1, Wih2, Whh2, b2, Wih3, Whh3, b3,
      Wih4, Whh4, b4, Wout, bout, out);
}

// Round 2
// 165.885 us; speedup vs baseline: 1.1577x; 1.1577x over previous
//
#include <hip/hip_runtime.h>

// LSTM autoencoder via bf16 MFMA, v10: NT=1024 (16 waves), BT=32, grid 256,
// 1 block/CU (v9 post-mortem: 2-block co-residency is refused by the CP ->
// raise waves/CU inside ONE workgroup: 12 -> 16 waves = 3 -> 4 waves/SIMD).
// Homogeneous wave work: phase A each wave = z1 tile w (both halves) + z2
// chain (tile w>>1, half w&1); phase B = z4 tile w (both halves) + z3 chain
// + rotating proj. Per-CU totals identical to v8 (48 cellUp, 144 MFMA/region).
// z3 input term Wih3*latent is constant across steps -> hoisted accumulator
// (z3: 2 MFMAs -> 1 per region).
// B=8192, T=30, F=16, H1=64, H2=32.
// log2e folded into weights/biases (gate-g rows x 2log2e); gates exp2(-acc).
// Fusion: sig(a)*tanh(b) = (1-eb) * rcp((1+ea)*(1+eb)).
// aB (stride 264 u16, 32 rows): phA h1 dbuf p*64, h2 dbuf 128+p*32, latent 160..191;
//                               phB h4 dbuf p*64, latent 160 (preserved), h3 192+p*32.
// LDS: xAll 32x968 (60.5KB) + aB 32x264 (16.5KB) = ~77KB -> 1 block/CU.

#define TT 30
#define FF 16
#define NT 1024

typedef unsigned short u16t;
typedef __attribute__((ext_vector_type(8))) short short8;
typedef __attribute__((ext_vector_type(4))) short short4v;
typedef __attribute__((ext_vector_type(4))) float floatx4;

#define MFMA(a, b, c) __builtin_amdgcn_mfma_f32_16x16x32_bf16(a, b, c, 0, 0, 0)

#if __has_builtin(__builtin_amdgcn_exp2f)
#define EXP2(x) __builtin_amdgcn_exp2f(x)
#else
#define EXP2(x) exp2f(x)
#endif

template <int P> struct IC { static constexpr int v = P; };

__device__ __forceinline__ float rcpf(float v) { return __builtin_amdgcn_rcpf(v); }
__device__ __forceinline__ u16t f2bf(float f) {
  unsigned int u = __float_as_uint(f);
  u = (u + 0x7FFFu + ((u >> 16) & 1u)) >> 16;
  return (u16t)u;
}
__device__ __forceinline__ short8 ldFragS(const float* p, float s) {
  const float4 lo = *(const float4*)p;
  const float4 hi = *(const float4*)(p + 4);
  short8 r;
  r[0] = (short)f2bf(lo.x * s); r[1] = (short)f2bf(lo.y * s);
  r[2] = (short)f2bf(lo.z * s); r[3] = (short)f2bf(lo.w * s);
  r[4] = (short)f2bf(hi.x * s); r[5] = (short)f2bf(hi.y * s);
  r[6] = (short)f2bf(hi.z * s); r[7] = (short)f2bf(hi.w * s);
  return r;
}
// acc pre-scaled: [i,f,o] x log2e, [g] x 2log2e. lane owns i,f,g,o of one unit.
__device__ __forceinline__ float cellUp(const floatx4 acc, float& c) {
  float ei = EXP2(-acc[0]);
  float ef = EXP2(-acc[1]);
  float eg = EXP2(-acc[2]);
  float eo = EXP2(-acc[3]);
  float fv = rcpf(1.f + ef);
  float P  = (1.f - eg) * rcpf((1.f + ei) * (1.f + eg));   // sig(i)*tanh(g)
  c = fv * c + P;
  float ec = EXP2(-2.885390082f * c);
  return (1.f - ec) * rcpf((1.f + eo) * (1.f + ec));       // sig(o)*tanh(c)
}

__global__ __launch_bounds__(NT, 4) void lstm_ae_mfma10(
    const float* __restrict__ x,
    const float* __restrict__ Wih1, const float* __restrict__ Whh1, const float* __restrict__ b1,
    const float* __restrict__ Wih2, const float* __restrict__ Whh2, const float* __restrict__ b2,
    const float* __restrict__ Wih3, const float* __restrict__ Whh3, const float* __restrict__ b3,
    const float* __restrict__ Wih4, const float* __restrict__ Whh4, const float* __restrict__ b4,
    const float* __restrict__ Wout, const float* __restrict__ bout,
    float* __restrict__ out)
{
  __shared__ __align__(16) u16t xAll[32 * 968];  // x bf16, k16..31 zero-pad, stride 968
  __shared__ __align__(16) u16t aB[32 * 264];    // recurrent state, stride 264

  const int t = threadIdx.x;
  const int w = t >> 6, lane = t & 63;           // 16 waves
  const int q = lane >> 4, n = lane & 15;
  const int q8 = q * 8;
  const int bBase = blockIdx.x * 32;
  const int nlo = n >> 2, ngt = n & 3;
  const int r0 = n * 264, r1 = (n + 16) * 264;   // two batch-half rows
  const int x0 = n * 968, x1 = (n + 16) * 968;
  const int tz = w >> 1, hz = w & 1;             // z2/z3 tile + half
  const int rz = hz ? r1 : r0;

  const float L1 = 1.442695041f, L2 = 2.885390082f;
  const float sA = (ngt == 2) ? L2 : L1;         // gate-g rows scaled 2log2e

  // ================= init =================
  for (int i = t; i < 32 * 264; i += NT) aB[i] = 0;
  {
    const float* xb = x + (size_t)bBase * (TT * FF);
    for (int i4 = t; i4 < 3840; i4 += NT) {
      int e = i4 * 4;
      int b = e / 480, r = e - b * 480;
      int stp = r >> 4, f = r & 15;
      float4 v = *(const float4*)&xb[e];
      short4v s4 = { (short)f2bf(v.x), (short)f2bf(v.y), (short)f2bf(v.z), (short)f2bf(v.w) };
      *(short4v*)&xAll[b * 968 + stp * 32 + f] = s4;
    }
    for (int i = t; i < 15360; i += NT) {   // zero pads k=16..31
      int b = i / 480, r = i - b * 480;
      int stp = r >> 4, f = r & 15;
      xAll[b * 968 + stp * 32 + 16 + f] = 0;
    }
  }
  const short8 z8 = { 0, 0, 0, 0, 0, 0, 0, 0 };
  // phase-A weights: every wave has one z1 tile (w) and one z2 chain (tz,hz)
  short8 w1f[3]; floatx4 bias1;
  {
    int row = ngt * 64 + w * 4 + nlo;
    w1f[0] = z8;
    if (q < 2) w1f[0] = ldFragS(&Wih1[row * 16 + q8], sA);
    w1f[1] = ldFragS(&Whh1[row * 64 + q8], sA);
    w1f[2] = ldFragS(&Whh1[row * 64 + 32 + q8], sA);
#pragma unroll
    for (int r = 0; r < 4; ++r) bias1[r] = b1[r * 64 + w * 4 + q] * (r == 2 ? L2 : L1);
  }
  short8 w2f[3]; floatx4 bias2;
  {
    int row = ngt * 32 + tz * 4 + nlo;
    w2f[0] = ldFragS(&Wih2[row * 64 + q8], sA);
    w2f[1] = ldFragS(&Wih2[row * 64 + 32 + q8], sA);
    w2f[2] = ldFragS(&Whh2[row * 32 + q8], sA);
#pragma unroll
    for (int r = 0; r < 4; ++r) bias2[r] = b2[r * 32 + tz * 4 + q] * (r == 2 ? L2 : L1);
  }
  __syncthreads();

  float cA[3] = {0.f, 0.f, 0.f};                 // z1 half0, z1 half1, z2
  short8 bxN[2];

  // ---- peel: z1(0) (h1(-1)=0) ----
  {
    const short8 bx0 = *(const short8*)&xAll[x0 + q8];
    const short8 bx1 = *(const short8*)&xAll[x1 + q8];
    floatx4 a0 = bias1, a1 = bias1;
    a0 = MFMA(w1f[0], bx0, a0);
    a1 = MFMA(w1f[0], bx1, a1);
    aB[r0 + w * 4 + q] = f2bf(cellUp(a0, cA[0]));
    aB[r1 + w * 4 + q] = f2bf(cellUp(a1, cA[1]));
    bxN[0] = *(const short8*)&xAll[x0 + 32 + q8];   // prefetch x(1)
    bxN[1] = *(const short8*)&xAll[x1 + 32 + q8];
  }
  __syncthreads();

  // ================= Phase A: 29 skewed regions, 1 barrier each =================
  auto stepA = [&](int st, auto pc) {
    constexpr int p = decltype(pc)::v;
    const short8 h1a0 = *(const short8*)&aB[r0 + p * 64 + q8];
    const short8 h1b0 = *(const short8*)&aB[r0 + p * 64 + 32 + q8];
    const short8 h1a1 = *(const short8*)&aB[r1 + p * 64 + q8];
    const short8 h1b1 = *(const short8*)&aB[r1 + p * 64 + 32 + q8];
    const short8 h1az = *(const short8*)&aB[rz + p * 64 + q8];
    const short8 h1bz = *(const short8*)&aB[rz + p * 64 + 32 + q8];
    const short8 h2z  = *(const short8*)&aB[rz + 128 + (1 - p) * 32 + q8];
    // z1(st+1), both halves
    floatx4 a0 = bias1, a1 = bias1;
    a0 = MFMA(w1f[0], bxN[0], a0);
    a1 = MFMA(w1f[0], bxN[1], a1);
    a0 = MFMA(w1f[1], h1a0, a0);
    a1 = MFMA(w1f[1], h1a1, a1);
    a0 = MFMA(w1f[2], h1b0, a0);
    a1 = MFMA(w1f[2], h1b1, a1);
    // z2(st), this wave's half
    floatx4 a2 = bias2;
    a2 = MFMA(w2f[0], h1az, a2);
    a2 = MFMA(w2f[1], h1bz, a2);
    a2 = MFMA(w2f[2], h2z, a2);
    aB[r0 + (1 - p) * 64 + w * 4 + q] = f2bf(cellUp(a0, cA[0]));
    aB[r1 + (1 - p) * 64 + w * 4 + q] = f2bf(cellUp(a1, cA[1]));
    aB[rz + 128 + p * 32 + tz * 4 + q] = f2bf(cellUp(a2, cA[2]));
    const int nx = (st + 2 < TT) ? st + 2 : TT - 1;
    bxN[0] = *(const short8*)&xAll[x0 + nx * 32 + q8];
    bxN[1] = *(const short8*)&xAll[x1 + nx * 32 + q8];
    __syncthreads();
  };
  for (int st = 0; st < 28; st += 2) { stepA(st, IC<0>{}); stepA(st + 1, IC<1>{}); }
  stepA(28, IC<0>{});
  // ---- tail: z2(29); h1(29)@64, h2(28)@128 -> latent 160..191 ----
  {
    const short8 h1az = *(const short8*)&aB[rz + 64 + q8];
    const short8 h1bz = *(const short8*)&aB[rz + 96 + q8];
    const short8 h2z  = *(const short8*)&aB[rz + 128 + q8];
    floatx4 a2 = bias2;
    a2 = MFMA(w2f[0], h1az, a2);
    a2 = MFMA(w2f[1], h1bz, a2);
    a2 = MFMA(w2f[2], h2z, a2);
    aB[rz + 160 + tz * 4 + q] = f2bf(cellUp(a2, cA[2]));
  }
  __syncthreads();

  // ================= transition: phase-B weights; zero h4(-1) =================
  short8 w4f[3]; floatx4 bias4;
  {
    int row = ngt * 64 + w * 4 + nlo;
    w4f[0] = ldFragS(&Wih4[row * 32 + q8], sA);
    w4f[1] = ldFragS(&Whh4[row * 64 + q8], sA);
    w4f[2] = ldFragS(&Whh4[row * 64 + 32 + q8], sA);
#pragma unroll
    for (int r = 0; r < 4; ++r) bias4[r] = b4[r * 64 + w * 4 + q] * (r == 2 ? L2 : L1);
  }
  short8 w3h; floatx4 acc3c;   // z3: hoisted const input term bias3 + Wih3*latent
  {
    int row = ngt * 32 + tz * 4 + nlo;
    const short8 w3i = ldFragS(&Wih3[row * 32 + q8], sA);
    w3h = ldFragS(&Whh3[row * 32 + q8], sA);
    floatx4 b3v;
#pragma unroll
    for (int r = 0; r < 4; ++r) b3v[r] = b3[r * 32 + tz * 4 + q] * (r == 2 ? L2 : L1);
    const short8 blat = *(const short8*)&aB[rz + 160 + q8];
    acc3c = MFMA(w3i, blat, b3v);
  }
  short8 wof[2]; floatx4 biasO;
  wof[0] = ldFragS(&Wout[n * 64 + q8], 1.f);
  wof[1] = ldFragS(&Wout[n * 64 + 32 + q8], 1.f);
  biasO = *(const floatx4*)&bout[q * 4];
  for (int i = t; i < 2048; i += NT) aB[(i >> 6) * 264 + 64 + (i & 63)] = 0;  // h4(-1)=0
  __syncthreads();

  float cB[3] = {0.f, 0.f, 0.f};                 // z4 half0, z4 half1, z3

  // ---- peel: z3(0) (h3(-1)=0 -> acc is just the hoisted const) ----
  aB[rz + 192 + tz * 4 + q] = f2bf(cellUp(acc3c, cB[2]));
  __syncthreads();

  // ================= Phase B: 29 skewed regions, 1 barrier each =================
  auto stepB = [&](int st, auto pc) {
    constexpr int p = decltype(pc)::v;
    const short8 h4a0 = *(const short8*)&aB[r0 + (1 - p) * 64 + q8];
    const short8 h4b0 = *(const short8*)&aB[r0 + (1 - p) * 64 + 32 + q8];
    const short8 h4a1 = *(const short8*)&aB[r1 + (1 - p) * 64 + q8];
    const short8 h4b1 = *(const short8*)&aB[r1 + (1 - p) * 64 + 32 + q8];
    const short8 h30  = *(const short8*)&aB[r0 + 192 + p * 32 + q8];
    const short8 h31  = *(const short8*)&aB[r1 + 192 + p * 32 + q8];
    const short8 h3z  = *(const short8*)&aB[rz + 192 + p * 32 + q8];
    // z4(st), both halves
    floatx4 a0 = bias4, a1 = bias4;
    a0 = MFMA(w4f[0], h30, a0);
    a1 = MFMA(w4f[0], h31, a1);
    a0 = MFMA(w4f[1], h4a0, a0);
    a1 = MFMA(w4f[1], h4a1, a1);
    a0 = MFMA(w4f[2], h4b0, a0);
    a1 = MFMA(w4f[2], h4b1, a1);
    // z3(st+1), this wave's half (input term hoisted)
    floatx4 a2 = MFMA(w3h, h3z, acc3c);
    aB[r0 + p * 64 + w * 4 + q] = f2bf(cellUp(a0, cB[0]));
    aB[r1 + p * 64 + w * 4 + q] = f2bf(cellUp(a1, cB[1]));
    aB[rz + 192 + (1 - p) * 32 + tz * 4 + q] = f2bf(cellUp(a2, cB[2]));
    if (st > 0 && w == ((st - 1) & 15)) {  // rotating proj(st-1)
      floatx4 y0 = biasO, y1 = biasO;
      y0 = MFMA(wof[0], h4a0, y0);
      y1 = MFMA(wof[0], h4a1, y1);
      y0 = MFMA(wof[1], h4b0, y0);
      y1 = MFMA(wof[1], h4b1, y1);
      *(floatx4*)&out[((size_t)(bBase + n) * TT + (st - 1)) * FF + q * 4] = y0;
      *(floatx4*)&out[((size_t)(bBase + n + 16) * TT + (st - 1)) * FF + q * 4] = y1;
    }
    __syncthreads();
  };
  for (int st = 0; st < 28; st += 2) { stepB(st, IC<0>{}); stepB(st + 1, IC<1>{}); }
  stepB(28, IC<0>{});
  // ---- tail: z4(29) (h3(29)@224, h4(28)@0); proj(28); proj(29) ----
  {
    const short8 h30  = *(const short8*)&aB[r0 + 224 + q8];
    const short8 h31  = *(const short8*)&aB[r1 + 224 + q8];
    const short8 h4a0 = *(const short8*)&aB[r0 + q8];
    const short8 h4b0 = *(const short8*)&aB[r0 + 32 + q8];
    const short8 h4a1 = *(const short8*)&aB[r1 + q8];
    const short8 h4b1 = *(const short8*)&aB[r1 + 32 + q8];
    floatx4 a0 = bias4, a1 = bias4;
    a0 = MFMA(w4f[0], h30, a0);
    a1 = MFMA(w4f[0], h31, a1);
    a0 = MFMA(w4f[1], h4a0, a0);
    a1 = MFMA(w4f[1], h4a1, a1);
    a0 = MFMA(w4f[2], h4b0, a0);
    a1 = MFMA(w4f[2], h4b1, a1);
    aB[r0 + 64 + w * 4 + q] = f2bf(cellUp(a0, cB[0]));
    aB[r1 + 64 + w * 4 + q] = f2bf(cellUp(a1, cB[1]));
    if (w == 12) {  // proj(28): (28 & 15) == 12
      floatx4 y0 = biasO, y1 = biasO;
      y0 = MFMA(wof[0], h4a0, y0);
      y1 = MFMA(wof[0], h4a1, y1);
      y0 = MFMA(wof[1], h4b0, y0);
      y1 = MFMA(wof[1], h4b1, y1);
      *(floatx4*)&out[((size_t)(bBase + n) * TT + 28) * FF + q * 4] = y0;
      *(floatx4*)&out[((size_t)(bBase + n + 16) * TT + 28) * FF + q * 4] = y1;
    }
  }
  __syncthreads();
  if (w == 13) {  // proj(29): h4(29)@64/96
    const short8 ba0 = *(const short8*)&aB[r0 + 64 + q8];
    const short8 bb0 = *(const short8*)&aB[r0 + 96 + q8];
    const short8 ba1 = *(const short8*)&aB[r1 + 64 + q8];
    const short8 bb1 = *(const short8*)&aB[r1 + 96 + q8];
    floatx4 y0 = biasO, y1 = biasO;
    y0 = MFMA(wof[0], ba0, y0);
    y1 = MFMA(wof[0], ba1, y1);
    y0 = MFMA(wof[1], bb0, y0);
    y1 = MFMA(wof[1], bb1, y1);
    *(floatx4*)&out[((size_t)(bBase + n) * TT + 29) * FF + q * 4] = y0;
    *(floatx4*)&out[((size_t)(bBase + n + 16) * TT + 29) * FF + q * 4] = y1;
  }
}

extern "C" void kernel_launch(void* const* d_in, const int* in_sizes, int n_in,
                              void* d_out, int out_size, void* d_ws, size_t ws_size,
                              hipStream_t stream) {
  const float* x    = (const float*)d_in[0];
  const float* Wih1 = (const float*)d_in[1];
  const float* Whh1 = (const float*)d_in[2];
  const float* b1   = (const float*)d_in[3];
  const float* Wih2 = (const float*)d_in[4];
  const float* Whh2 = (const float*)d_in[5];
  const float* b2   = (const float*)d_in[6];
  const float* Wih3 = (const float*)d_in[7];
  const float* Whh3 = (const float*)d_in[8];
  const float* b3   = (const float*)d_in[9];
  const float* Wih4 = (const float*)d_in[10];
  const float* Whh4 = (const float*)d_in[11];
  const float* b4   = (const float*)d_in[12];
  const float* Wout = (const float*)d_in[13];
  const float* bout = (const float*)d_in[14];
  float* out = (float*)d_out;

  const int B = in_sizes[0] / (TT * FF);   // 8192
  dim3 grid(B / 32), block(NT);
  lstm_ae_mfma10<<<grid, block, 0, stream>>>(
      x, Wih1, Whh1, b1, Wih2, Whh2, b2, Wih3, Whh3, b3,
      Wih4, Whh4, b4, Wout, bout, out);
}

// Round 3
// 156.148 us; speedup vs baseline: 1.2299x; 1.0624x over previous
//
#include <hip/hip_runtime.h>

// LSTM autoencoder via bf16 MFMA, v11: v8 geometry (768 thr, 12 waves, grid 256,
// 1 block/CU) + per-cell issue-cost cuts. v8/v9/v10 post-mortem: total VALU+trans
// issue is invariant ~43us and ~= 720 wave-cellUps/SIMD x (8 trans x 16cyc + 30);
// kernel is transcendental-issue bound. Cuts:
//  - cellUp merged-rcp: 5 exp2 + 2 rcp (was 3 rcp) via common denominator.
//  - v_cvt_pk_bf16_f32 packs tile-pair h conversion (1 op vs 2x4-op f2bf).
//  - raw lgkmcnt-only barrier in steady-state regions (no vmcnt(0) drain ->
//    proj wave's global stores don't straggle the barrier).
//  - z3 input term b3 + Wih3*latent hoisted (step-invariant): z3 = 1 MFMA/chain.
// B=8192, T=30, F=16, H1=64, H2=32.
// Per step phase A: waves 0..7: z1 tiles {w,w+8} x2 halves; waves 8..11: z2 x2.
// Phase B: waves 0..7: z4 {w,w+8} x2 + rotating proj x2; waves 8..11: z3 x2.
// log2e folded into weights/biases (gate-g rows x 2log2e); gates exp2(-acc).
// aB (stride 264 u16, 32 rows): phA h1 dbuf p*64, h2 dbuf 128+p*32, latent 160..191;
//                               phB h4 dbuf p*64, latent 160 (preserved), h3 192+p*32.
// LDS: xAll 32x968 (60.5KB) + aB 32x264 (16.5KB) = ~77KB -> 1 block/CU.

#define TT 30
#define FF 16
#define NT 768

typedef unsigned short u16t;
typedef __attribute__((ext_vector_type(8))) short short8;
typedef __attribute__((ext_vector_type(4))) short short4v;
typedef __attribute__((ext_vector_type(4))) float floatx4;

#define MFMA(a, b, c) __builtin_amdgcn_mfma_f32_16x16x32_bf16(a, b, c, 0, 0, 0)

#if __has_builtin(__builtin_amdgcn_exp2f)
#define EXP2(x) __builtin_amdgcn_exp2f(x)
#else
#define EXP2(x) exp2f(x)
#endif

template <int P> struct IC { static constexpr int v = P; };

__device__ __forceinline__ float rcpf(float v) { return __builtin_amdgcn_rcpf(v); }
__device__ __forceinline__ u16t f2bf(float f) {
  unsigned int u = __float_as_uint(f);
  u = (u + 0x7FFFu + ((u >> 16) & 1u)) >> 16;
  return (u16t)u;
}
// packed f32x2 -> bf16x2 (RNE), one VALU op
__device__ __forceinline__ unsigned int pkbf(float a, float b) {
  unsigned int r;
  asm("v_cvt_pk_bf16_f32 %0, %1, %2" : "=v"(r) : "v"(a), "v"(b));
  return r;
}
// LDS-only barrier: wait ds ops, skip vmcnt drain (__syncthreads drains vmcnt(0),
// which makes the proj wave's outstanding global stores a barrier straggler).
__device__ __forceinline__ void barLDS() {
  asm volatile("s_waitcnt lgkmcnt(0)" ::: "memory");
  __builtin_amdgcn_s_barrier();
}
__device__ __forceinline__ short8 ldFragS(const float* p, float s) {
  const float4 lo = *(const float4*)p;
  const float4 hi = *(const float4*)(p + 4);
  short8 r;
  r[0] = (short)f2bf(lo.x * s); r[1] = (short)f2bf(lo.y * s);
  r[2] = (short)f2bf(lo.z * s); r[3] = (short)f2bf(lo.w * s);
  r[4] = (short)f2bf(hi.x * s); r[5] = (short)f2bf(hi.y * s);
  r[6] = (short)f2bf(hi.z * s); r[7] = (short)f2bf(hi.w * s);
  return r;
}
// acc pre-scaled: [i,f,o] x log2e, [g] x 2log2e. lane owns i,f,g,o of one unit.
// Merged-rcp form: 5 exp2 + 2 rcp (trans issue 7x16cyc vs 8x16).
// c = [c(1+ei)(1+eg) + (1-eg)(1+ef)] / [(1+ef)(1+ei)(1+eg)]
__device__ __forceinline__ float cellUp(const floatx4 acc, float& c) {
  float ei = EXP2(-acc[0]);
  float ef = EXP2(-acc[1]);
  float eg = EXP2(-acc[2]);
  float eo = EXP2(-acc[3]);
  float pig = (1.f + ei) * (1.f + eg);
  float pf  = 1.f + ef;
  float num = c * pig + (1.f - eg) * pf;
  c = num * rcpf(pf * pig);
  float ec = EXP2(-2.885390082f * c);
  return (1.f - ec) * rcpf((1.f + eo) * (1.f + ec));       // sig(o)*tanh(c)
}

__global__ __launch_bounds__(NT, 3) void lstm_ae_mfma11(
    const float* __restrict__ x,
    const float* __restrict__ Wih1, const float* __restrict__ Whh1, const float* __restrict__ b1,
    const float* __restrict__ Wih2, const float* __restrict__ Whh2, const float* __restrict__ b2,
    const float* __restrict__ Wih3, const float* __restrict__ Whh3, const float* __restrict__ b3,
    const float* __restrict__ Wih4, const float* __restrict__ Whh4, const float* __restrict__ b4,
    const float* __restrict__ Wout, const float* __restrict__ bout,
    float* __restrict__ out)
{
  __shared__ __align__(16) u16t xAll[32 * 968];  // x bf16, k16..31 zero-pad, stride 968
  __shared__ __align__(16) u16t aB[32 * 264];    // recurrent state, stride 264

  const int t = threadIdx.x;
  const int w = t >> 6, lane = t & 63;           // 12 waves
  const int q = lane >> 4, n = lane & 15;
  const int q8 = q * 8;
  const int bBase = blockIdx.x * 32;
  const int nlo = n >> 2, ngt = n & 3;
  const int r0 = n * 264, r1 = (n + 16) * 264;   // two batch-half rows
  const int x0 = n * 968, x1 = (n + 16) * 968;
  const bool isZ1 = (w < 8);
  const int u = w & 3;                           // for waves 8..11

  const float L1 = 1.442695041f, L2 = 2.885390082f;
  const float sA = (ngt == 2) ? L2 : L1;         // gate-g rows scaled 2log2e

  // ================= init =================
  for (int i = t; i < 32 * 264; i += NT) aB[i] = 0;
  {
    const float* xb = x + (size_t)bBase * (TT * FF);
    for (int i4 = t; i4 < 3840; i4 += NT) {
      int e = i4 * 4;
      int b = e / 480, r = e - b * 480;
      int stp = r >> 4, f = r & 15;
      float4 v = *(const float4*)&xb[e];
      short4v s4 = { (short)f2bf(v.x), (short)f2bf(v.y), (short)f2bf(v.z), (short)f2bf(v.w) };
      *(short4v*)&xAll[b * 968 + stp * 32 + f] = s4;
    }
    for (int i = t; i < 15360; i += NT) {   // zero pads k=16..31
      int b = i / 480, r = i - b * 480;
      int stp = r >> 4, f = r & 15;
      xAll[b * 968 + stp * 32 + 16 + f] = 0;
    }
  }
  const short8 z8 = { 0, 0, 0, 0, 0, 0, 0, 0 };
  short8 wAf[2][3]; floatx4 biasA[2];            // z1 (waves 0..7) or z2 (waves 8..11)
  if (isZ1) {
#pragma unroll
    for (int tt = 0; tt < 2; ++tt) {
      int T = w + 8 * tt;
      int row = ngt * 64 + T * 4 + nlo;
      wAf[tt][0] = z8;
      if (q < 2) wAf[tt][0] = ldFragS(&Wih1[row * 16 + q8], sA);
      wAf[tt][1] = ldFragS(&Whh1[row * 64 + q8], sA);
      wAf[tt][2] = ldFragS(&Whh1[row * 64 + 32 + q8], sA);
#pragma unroll
      for (int r = 0; r < 4; ++r) biasA[tt][r] = b1[r * 64 + T * 4 + q] * (r == 2 ? L2 : L1);
    }
  } else {
#pragma unroll
    for (int tt = 0; tt < 2; ++tt) {
      int T = 2 * u + tt;
      int row = ngt * 32 + T * 4 + nlo;
      wAf[tt][0] = ldFragS(&Wih2[row * 64 + q8], sA);
      wAf[tt][1] = ldFragS(&Wih2[row * 64 + 32 + q8], sA);
      wAf[tt][2] = ldFragS(&Whh2[row * 32 + q8], sA);
#pragma unroll
      for (int r = 0; r < 4; ++r) biasA[tt][r] = b2[r * 32 + T * 4 + q] * (r == 2 ? L2 : L1);
    }
  }
  __syncthreads();

  float cA[2][2] = {{0.f, 0.f}, {0.f, 0.f}};     // [half][tile]
  short8 bxN[2];
  float h0v[2], h1v[2];

  // ---- peel: z1(0) (h1(-1)=0) ----
  if (isZ1) {
    const short8 bx0 = *(const short8*)&xAll[x0 + q8];
    const short8 bx1 = *(const short8*)&xAll[x1 + q8];
#pragma unroll
    for (int tt = 0; tt < 2; ++tt) {
      floatx4 a0 = biasA[tt], a1 = biasA[tt];
      a0 = MFMA(wAf[tt][0], bx0, a0);
      a1 = MFMA(wAf[tt][0], bx1, a1);
      h0v[tt] = cellUp(a0, cA[0][tt]);
      h1v[tt] = cellUp(a1, cA[1][tt]);
    }
    unsigned int pk0 = pkbf(h0v[0], h0v[1]);
    unsigned int pk1 = pkbf(h1v[0], h1v[1]);
    aB[r0 + w * 4 + q] = (u16t)pk0;
    aB[r0 + (w + 8) * 4 + q] = (u16t)(pk0 >> 16);
    aB[r1 + w * 4 + q] = (u16t)pk1;
    aB[r1 + (w + 8) * 4 + q] = (u16t)(pk1 >> 16);
    bxN[0] = *(const short8*)&xAll[x0 + 32 + q8];   // prefetch x(1)
    bxN[1] = *(const short8*)&xAll[x1 + 32 + q8];
  }
  barLDS();

  // ================= Phase A: 29 skewed regions, 1 barrier each =================
  auto stepA = [&](int st, auto pc) {
    constexpr int p = decltype(pc)::v;
    const short8 h1a0 = *(const short8*)&aB[r0 + p * 64 + q8];
    const short8 h1b0 = *(const short8*)&aB[r0 + p * 64 + 32 + q8];
    const short8 h1a1 = *(const short8*)&aB[r1 + p * 64 + q8];
    const short8 h1b1 = *(const short8*)&aB[r1 + p * 64 + 32 + q8];
    if (isZ1) {  // z1(st+1) x2 halves
#pragma unroll
      for (int tt = 0; tt < 2; ++tt) {
        floatx4 a0 = biasA[tt], a1 = biasA[tt];
        a0 = MFMA(wAf[tt][0], bxN[0], a0);
        a1 = MFMA(wAf[tt][0], bxN[1], a1);
        a0 = MFMA(wAf[tt][1], h1a0, a0);
        a1 = MFMA(wAf[tt][1], h1a1, a1);
        a0 = MFMA(wAf[tt][2], h1b0, a0);
        a1 = MFMA(wAf[tt][2], h1b1, a1);
        h0v[tt] = cellUp(a0, cA[0][tt]);
        h1v[tt] = cellUp(a1, cA[1][tt]);
      }
      unsigned int pk0 = pkbf(h0v[0], h0v[1]);
      unsigned int pk1 = pkbf(h1v[0], h1v[1]);
      aB[r0 + (1 - p) * 64 + w * 4 + q] = (u16t)pk0;
      aB[r0 + (1 - p) * 64 + (w + 8) * 4 + q] = (u16t)(pk0 >> 16);
      aB[r1 + (1 - p) * 64 + w * 4 + q] = (u16t)pk1;
      aB[r1 + (1 - p) * 64 + (w + 8) * 4 + q] = (u16t)(pk1 >> 16);
      const int nx = (st + 2 < TT) ? st + 2 : TT - 1;
      bxN[0] = *(const short8*)&xAll[x0 + nx * 32 + q8];
      bxN[1] = *(const short8*)&xAll[x1 + nx * 32 + q8];
    } else {     // z2(st) x2 halves
      const short8 h20 = *(const short8*)&aB[r0 + 128 + (1 - p) * 32 + q8];
      const short8 h21 = *(const short8*)&aB[r1 + 128 + (1 - p) * 32 + q8];
#pragma unroll
      for (int tt = 0; tt < 2; ++tt) {
        floatx4 a0 = biasA[tt], a1 = biasA[tt];
        a0 = MFMA(wAf[tt][0], h1a0, a0);
        a1 = MFMA(wAf[tt][0], h1a1, a1);
        a0 = MFMA(wAf[tt][1], h1b0, a0);
        a1 = MFMA(wAf[tt][1], h1b1, a1);
        a0 = MFMA(wAf[tt][2], h20, a0);
        a1 = MFMA(wAf[tt][2], h21, a1);
        h0v[tt] = cellUp(a0, cA[0][tt]);
        h1v[tt] = cellUp(a1, cA[1][tt]);
      }
      unsigned int pk0 = pkbf(h0v[0], h0v[1]);
      unsigned int pk1 = pkbf(h1v[0], h1v[1]);
      aB[r0 + 128 + p * 32 + (2 * u) * 4 + q] = (u16t)pk0;
      aB[r0 + 128 + p * 32 + (2 * u + 1) * 4 + q] = (u16t)(pk0 >> 16);
      aB[r1 + 128 + p * 32 + (2 * u) * 4 + q] = (u16t)pk1;
      aB[r1 + 128 + p * 32 + (2 * u + 1) * 4 + q] = (u16t)(pk1 >> 16);
    }
    barLDS();
  };
  for (int st = 0; st < 28; st += 2) { stepA(st, IC<0>{}); stepA(st + 1, IC<1>{}); }
  stepA(28, IC<0>{});
  // ---- tail: z2(29); h1(29)@64, h2(28)@128 -> latent 160..191 ----
  if (!isZ1) {
    const short8 h1a0 = *(const short8*)&aB[r0 + 64 + q8];
    const short8 h1b0 = *(const short8*)&aB[r0 + 96 + q8];
    const short8 h1a1 = *(const short8*)&aB[r1 + 64 + q8];
    const short8 h1b1 = *(const short8*)&aB[r1 + 96 + q8];
    const short8 h20  = *(const short8*)&aB[r0 + 128 + q8];
    const short8 h21  = *(const short8*)&aB[r1 + 128 + q8];
#pragma unroll
    for (int tt = 0; tt < 2; ++tt) {
      floatx4 a0 = biasA[tt], a1 = biasA[tt];
      a0 = MFMA(wAf[tt][0], h1a0, a0);
      a1 = MFMA(wAf[tt][0], h1a1, a1);
      a0 = MFMA(wAf[tt][1], h1b0, a0);
      a1 = MFMA(wAf[tt][1], h1b1, a1);
      a0 = MFMA(wAf[tt][2], h20, a0);
      a1 = MFMA(wAf[tt][2], h21, a1);
      h0v[tt] = cellUp(a0, cA[0][tt]);
      h1v[tt] = cellUp(a1, cA[1][tt]);
    }
    unsigned int pk0 = pkbf(h0v[0], h0v[1]);
    unsigned int pk1 = pkbf(h1v[0], h1v[1]);
    aB[r0 + 160 + (2 * u) * 4 + q] = (u16t)pk0;
    aB[r0 + 160 + (2 * u + 1) * 4 + q] = (u16t)(pk0 >> 16);
    aB[r1 + 160 + (2 * u) * 4 + q] = (u16t)pk1;
    aB[r1 + 160 + (2 * u + 1) * 4 + q] = (u16t)(pk1 >> 16);
  }
  __syncthreads();

  // ================= transition: phase-B weights; zero h4(-1) =================
  short8 wBf[2][3]; floatx4 biasB[2];
  short8 wof[2]; floatx4 biasO;
  short8 w3h[2]; floatx4 acc3c[2][2];            // z3: hoisted b3 + Wih3*latent [tt][half]
  if (isZ1) {
#pragma unroll
    for (int tt = 0; tt < 2; ++tt) {
      int T = w + 8 * tt;
      int row = ngt * 64 + T * 4 + nlo;
      wBf[tt][0] = ldFragS(&Wih4[row * 32 + q8], sA);
      wBf[tt][1] = ldFragS(&Whh4[row * 64 + q8], sA);
      wBf[tt][2] = ldFragS(&Whh4[row * 64 + 32 + q8], sA);
#pragma unroll
      for (int r = 0; r < 4; ++r) biasB[tt][r] = b4[r * 64 + T * 4 + q] * (r == 2 ? L2 : L1);
    }
    wof[0] = ldFragS(&Wout[n * 64 + q8], 1.f);
    wof[1] = ldFragS(&Wout[n * 64 + 32 + q8], 1.f);
    biasO = *(const floatx4*)&bout[q * 4];
  } else {
    const short8 blat0 = *(const short8*)&aB[r0 + 160 + q8];
    const short8 blat1 = *(const short8*)&aB[r1 + 160 + q8];
#pragma unroll
    for (int tt = 0; tt < 2; ++tt) {
      int T = 2 * u + tt;
      int row = ngt * 32 + T * 4 + nlo;
      const short8 w3i = ldFragS(&Wih3[row * 32 + q8], sA);
      w3h[tt] = ldFragS(&Whh3[row * 32 + q8], sA);
      floatx4 b3v;
#pragma unroll
      for (int r = 0; r < 4; ++r) b3v[r] = b3[r * 32 + T * 4 + q] * (r == 2 ? L2 : L1);
      acc3c[tt][0] = MFMA(w3i, blat0, b3v);
      acc3c[tt][1] = MFMA(w3i, blat1, b3v);
    }
  }
  for (int i = t; i < 2048; i += NT) aB[(i >> 6) * 264 + 64 + (i & 63)] = 0;  // h4(-1)=0
  __syncthreads();

  float cB[2][2] = {{0.f, 0.f}, {0.f, 0.f}};

  // ---- peel: z3(0) (h3(-1)=0 -> acc is the hoisted const) ----
  if (!isZ1) {
#pragma unroll
    for (int tt = 0; tt < 2; ++tt) {
      h0v[tt] = cellUp(acc3c[tt][0], cB[0][tt]);
      h1v[tt] = cellUp(acc3c[tt][1], cB[1][tt]);
    }
    unsigned int pk0 = pkbf(h0v[0], h0v[1]);
    unsigned int pk1 = pkbf(h1v[0], h1v[1]);
    aB[r0 + 192 + (2 * u) * 4 + q] = (u16t)pk0;
    aB[r0 + 192 + (2 * u + 1) * 4 + q] = (u16t)(pk0 >> 16);
    aB[r1 + 192 + (2 * u) * 4 + q] = (u16t)pk1;
    aB[r1 + 192 + (2 * u + 1) * 4 + q] = (u16t)(pk1 >> 16);
  }
  barLDS();

  // ================= Phase B: 29 skewed regions, 1 barrier each =================
  auto stepB = [&](int st, auto pc) {
    constexpr int p = decltype(pc)::v;
    const short8 h30 = *(const short8*)&aB[r0 + 192 + p * 32 + q8];
    const short8 h31 = *(const short8*)&aB[r1 + 192 + p * 32 + q8];
    if (isZ1) {  // z4(st) x2 + rotating proj(st-1) x2
      const short8 h4a0 = *(const short8*)&aB[r0 + (1 - p) * 64 + q8];
      const short8 h4b0 = *(const short8*)&aB[r0 + (1 - p) * 64 + 32 + q8];
      const short8 h4a1 = *(const short8*)&aB[r1 + (1 - p) * 64 + q8];
      const short8 h4b1 = *(const short8*)&aB[r1 + (1 - p) * 64 + 32 + q8];
#pragma unroll
      for (int tt = 0; tt < 2; ++tt) {
        floatx4 a0 = biasB[tt], a1 = biasB[tt];
        a0 = MFMA(wBf[tt][0], h30, a0);
        a1 = MFMA(wBf[tt][0], h31, a1);
        a0 = MFMA(wBf[tt][1], h4a0, a0);
        a1 = MFMA(wBf[tt][1], h4a1, a1);
        a0 = MFMA(wBf[tt][2], h4b0, a0);
        a1 = MFMA(wBf[tt][2], h4b1, a1);
        h0v[tt] = cellUp(a0, cB[0][tt]);
        h1v[tt] = cellUp(a1, cB[1][tt]);
      }
      unsigned int pk0 = pkbf(h0v[0], h0v[1]);
      unsigned int pk1 = pkbf(h1v[0], h1v[1]);
      aB[r0 + p * 64 + w * 4 + q] = (u16t)pk0;
      aB[r0 + p * 64 + (w + 8) * 4 + q] = (u16t)(pk0 >> 16);
      aB[r1 + p * 64 + w * 4 + q] = (u16t)pk1;
      aB[r1 + p * 64 + (w + 8) * 4 + q] = (u16t)(pk1 >> 16);
      if (st > 0 && w == ((st - 1) & 7)) {
        floatx4 y0 = biasO, y1 = biasO;
        y0 = MFMA(wof[0], h4a0, y0);
        y1 = MFMA(wof[0], h4a1, y1);
        y0 = MFMA(wof[1], h4b0, y0);
        y1 = MFMA(wof[1], h4b1, y1);
        *(floatx4*)&out[((size_t)(bBase + n) * TT + (st - 1)) * FF + q * 4] = y0;
        *(floatx4*)&out[((size_t)(bBase + n + 16) * TT + (st - 1)) * FF + q * 4] = y1;
      }
    } else {     // z3(st+1) x2 (input term hoisted)
#pragma unroll
      for (int tt = 0; tt < 2; ++tt) {
        floatx4 a0 = MFMA(w3h[tt], h30, acc3c[tt][0]);
        floatx4 a1 = MFMA(w3h[tt], h31, acc3c[tt][1]);
        h0v[tt] = cellUp(a0, cB[0][tt]);
        h1v[tt] = cellUp(a1, cB[1][tt]);
      }
      unsigned int pk0 = pkbf(h0v[0], h0v[1]);
      unsigned int pk1 = pkbf(h1v[0], h1v[1]);
      aB[r0 + 192 + (1 - p) * 32 + (2 * u) * 4 + q] = (u16t)pk0;
      aB[r0 + 192 + (1 - p) * 32 + (2 * u + 1) * 4 + q] = (u16t)(pk0 >> 16);
      aB[r1 + 192 + (1 - p) * 32 + (2 * u) * 4 + q] = (u16t)pk1;
      aB[r1 + 192 + (1 - p) * 32 + (2 * u + 1) * 4 + q] = (u16t)(pk1 >> 16);
    }
    barLDS();
  };
  for (int st = 0; st < 28; st += 2) { stepB(st, IC<0>{}); stepB(st + 1, IC<1>{}); }
  stepB(28, IC<0>{});
  // ---- tail: z4(29) (h3(29)@224, h4(28)@0); proj(28); proj(29) ----
  if (isZ1) {
    const short8 h30  = *(const short8*)&aB[r0 + 224 + q8];
    const short8 h31  = *(const short8*)&aB[r1 + 224 + q8];
    const short8 h4a0 = *(const short8*)&aB[r0 + q8];
    const short8 h4b0 = *(const short8*)&aB[r0 + 32 + q8];
    const short8 h4a1 = *(const short8*)&aB[r1 + q8];
    const short8 h4b1 = *(const short8*)&aB[r1 + 32 + q8];
#pragma unroll
    for (int tt = 0; tt < 2; ++tt) {
      floatx4 a0 = biasB[tt], a1 = biasB[tt];
      a0 = MFMA(wBf[tt][0], h30, a0);
      a1 = MFMA(wBf[tt][0], h31, a1);
      a0 = MFMA(wBf[tt][1], h4a0, a0);
      a1 = MFMA(wBf[tt][1], h4a1, a1);
      a0 = MFMA(wBf[tt][2], h4b0, a0);
      a1 = MFMA(wBf[tt][2], h4b1, a1);
      h0v[tt] = cellUp(a0, cB[0][tt]);
      h1v[tt] = cellUp(a1, cB[1][tt]);
    }
    unsigned int pk0 = pkbf(h0v[0], h0v[1]);
    unsigned int pk1 = pkbf(h1v[0], h1v[1]);
    aB[r0 + 64 + w * 4 + q] = (u16t)pk0;
    aB[r0 + 64 + (w + 8) * 4 + q] = (u16t)(pk0 >> 16);
    aB[r1 + 64 + w * 4 + q] = (u16t)pk1;
    aB[r1 + 64 + (w + 8) * 4 + q] = (u16t)(pk1 >> 16);
    if (w == 4) {  // proj(28)
      floatx4 y0 = biasO, y1 = biasO;
      y0 = MFMA(wof[0], h4a0, y0);
      y1 = MFMA(wof[0], h4a1, y1);
      y0 = MFMA(wof[1], h4b0, y0);
      y1 = MFMA(wof[1], h4b1, y1);
      *(floatx4*)&out[((size_t)(bBase + n) * TT + 28) * FF + q * 4] = y0;
      *(floatx4*)&out[((size_t)(bBase + n + 16) * TT + 28) * FF + q * 4] = y1;
    }
  }
  barLDS();
  if (w == 5) {  // proj(29): h4(29)@64/96
    const short8 ba0 = *(const short8*)&aB[r0 + 64 + q8];
    const short8 bb0 = *(const short8*)&aB[r0 + 96 + q8];
    const short8 ba1 = *(const short8*)&aB[r1 + 64 + q8];
    const short8 bb1 = *(const short8*)&aB[r1 + 96 + q8];
    floatx4 y0 = biasO, y1 = biasO;
    y0 = MFMA(wof[0], ba0, y0);
    y1 = MFMA(wof[0], ba1, y1);
    y0 = MFMA(wof[1], bb0, y0);
    y1 = MFMA(wof[1], bb1, y1);
    *(floatx4*)&out[((size_t)(bBase + n) * TT + 29) * FF + q * 4] = y0;
    *(floatx4*)&out[((size_t)(bBase + n + 16) * TT + 29) * FF + q * 4] = y1;
  }
}

extern "C" void kernel_launch(void* const* d_in, const int* in_sizes, int n_in,
                              void* d_out, int out_size, void* d_ws, size_t ws_size,
                              hipStream_t stream) {
  const float* x    = (const float*)d_in[0];
  const float* Wih1 = (const float*)d_in[1];
  const float* Whh1 = (const float*)d_in[2];
  const float* b1   = (const float*)d_in[3];
  const float* Wih2 = (const float*)d_in[4];
  const float* Whh2 = (const float*)d_in[5];
  const float* b2   = (const float*)d_in[6];
  const float* Wih3 = (const float*)d_in[7];
  const float* Whh3 = (const float*)d_in[8];
  const float* b3   = (const float*)d_in[9];
  const float* Wih4 = (const float*)d_in[10];
  const float* Whh4 = (const float*)d_in[11];
  const float* b4   = (const float*)d_in[12];
  const float* Wout = (const float*)d_in[13];
  const float* bout = (const float*)d_in[14];
  float* out = (float*)d_out;

  const int B = in_sizes[0] / (TT * FF);   // 8192
  dim3 grid(B / 32), block(NT);
  lstm_ae_mfma11<<<grid, block, 0, stream>>>(
      x, Wih1, Whh1, b1, Wih2, Whh2, b2, Wih3, Whh3, b3,
      Wih4, Whh4, b4, Wout, bout, out);
}